// Round 12
// baseline (66.390 us; speedup 1.0000x reference)
//
#include <hip/hip_runtime.h>

#define B 8
#define T 2048
#define D 256
#define L 8
#define E 64
#define BT (B*T)

typedef _Float16 f16;
typedef f16 f16x8 __attribute__((ext_vector_type(8)));
typedef float f32x4 __attribute__((ext_vector_type(4)));
typedef float f32x16 __attribute__((ext_vector_type(16)));

// workspace layout (float offsets)
#define OFF_I   0
#define OFF_F   (OFF_I  + B*L*T)            // fp32
#define OFF_WT  (OFF_F  + B*L*T)            // f16 16*E*D
#define OFF_VT  (OFF_WT + 16*E*D/2)         // f16 B*L*E*T
#define OFF_KT  (OFF_VT + B*L*E*T/2)
#define OFF_CP  (OFF_KT + B*L*E*T/2)        // fp32 64*4*4160
#define OFF_X16 (OFF_CP + 64*4*4160)        // f16 BT*D

// ---------------------------------------------------------------------------
// K1: fused prep.  bx<512: i/f projection; 512..527: v/k weight transpose;
//     528..2575: x fp32->f16 conversion.   (R11-proven, unchanged)
// ---------------------------------------------------------------------------
__global__ __launch_bounds__(256) void k_prep_all(const float* __restrict__ x,
        const float* __restrict__ Wlin, const float* __restrict__ blin,
        const float* __restrict__ Wml,
        float* __restrict__ ibuf, float* __restrict__ fbuf,
        f16* __restrict__ Wt16, f16* __restrict__ x16) {
    __shared__ __align__(16) char smem[49920];
    int tid = threadIdx.x;
    int bx = blockIdx.x;
    if (bx < 512) {
        float (*xs)[260] = (float(*)[260])smem;            // 32 x 260
        float (*wsm)[260] = (float(*)[260])(smem + 33280); // 16 x 260
        int t0 = bx * 32;
        {
            int row = tid >> 3, q = tid & 7;
            const float* src = x + (size_t)(t0 + row) * D + q * 32;
            #pragma unroll
            for (int j = 0; j < 8; ++j) {
                float4 v = *(const float4*)(src + j * 4);
                *(float4*)&xs[row][q * 32 + j * 4] = v;
            }
        }
        {
            int row = tid >> 4, c0 = (tid & 15) * 16;
            const float* src = Wlin + row * D + c0;
            #pragma unroll
            for (int j = 0; j < 4; ++j) {
                float4 v = *(const float4*)(src + j * 4);
                *(float4*)&wsm[row][c0 + j * 4] = v;
            }
        }
        __syncthreads();
        int tl = tid >> 4, g = tid & 15;
        float acc0 = 0.f, acc1 = 0.f;
        for (int i = 0; i < D; ++i) {
            float wv = wsm[g][i];
            acc0 += xs[tl * 2 + 0][i] * wv;
            acc1 += xs[tl * 2 + 1][i] * wv;
        }
        float bias = blin[g];
        float acc[2] = {acc0 + bias, acc1 + bias};
        #pragma unroll
        for (int u = 0; u < 2; ++u) {
            int t = t0 + tl * 2 + u;
            int b = t >> 11, tt = t & 2047;
            if (g < 8) ibuf[(b * L + g) * T + tt] = acc[u];
            else       fbuf[(b * L + (g - 8)) * T + tt] = acc[u];
        }
    } else if (bx < 528) {
        float (*ts)[65] = (float(*)[65])smem;              // 64 x 65
        int vkrow = bx - 512;
        int wrow = 8 + vkrow;
        for (int dc = 0; dc < 4; ++dc) {
            int d0 = dc * 64;
            int r = tid >> 2, cq = (tid & 3) * 16;
            const float* src = Wml + ((size_t)wrow * D + d0 + r) * E + cq;
            #pragma unroll
            for (int j = 0; j < 16; j += 4) {
                float4 v = *(const float4*)(src + j);
                ts[r][cq + j] = v.x; ts[r][cq + j + 1] = v.y;
                ts[r][cq + j + 2] = v.z; ts[r][cq + j + 3] = v.w;
            }
            __syncthreads();
            int e = tid >> 2, dq = (tid & 3) * 16;
            f16* dst = Wt16 + ((size_t)vkrow * E + e) * D + d0 + dq;
            f16x8 o0, o1;
            #pragma unroll
            for (int j = 0; j < 8; ++j) {
                o0[j] = (f16)ts[dq + j][e];
                o1[j] = (f16)ts[dq + 8 + j][e];
            }
            *(f16x8*)dst = o0;
            *(f16x8*)(dst + 8) = o1;
            __syncthreads();
        }
    } else {
        int i = ((bx - 528) * 256 + tid) * 8;
        float4 v0 = *(const float4*)(x + i);
        float4 v1 = *(const float4*)(x + i + 4);
        f16x8 o;
        o[0] = (f16)v0.x; o[1] = (f16)v0.y; o[2] = (f16)v0.z; o[3] = (f16)v0.w;
        o[4] = (f16)v1.x; o[5] = (f16)v1.y; o[6] = (f16)v1.z; o[7] = (f16)v1.w;
        *(f16x8*)(x16 + i) = o;
    }
}

// ---------------------------------------------------------------------------
// K2: v,k projection, now with 32x32x16 MFMA (same tile/staging/LDS as R11).
// Tile 128(M) x 512(N), BK=32, 512 thr.  grid (BT/128, 2).  Output (e,t).
// ---------------------------------------------------------------------------
__global__ __launch_bounds__(512) void k_vkproj4(const f16* __restrict__ x16,
        const f16* __restrict__ Wt16, const float* __restrict__ bml,
        f16* __restrict__ Vt, f16* __restrict__ Kt) {
    __shared__ __align__(16) char lds[40960];   // As 8KB | Bs 32KB
    int tid = threadIdx.x;
    int bx = blockIdx.x, h = blockIdx.y;
    int t0 = bx * 128;
    const f16* xa = x16 + (size_t)t0 * D;
    const f16* wb = Wt16 + (size_t)h * 8 * E * D;
    int wv = tid >> 6, lane = tid & 63;
    int wr = wv >> 2, wc = wv & 3;
    int l5 = lane & 31, hk = lane >> 5;
    int sa_t = tid >> 2, sa_q = tid & 3;
    f32x16 acc[2][4] = {};   // [fm: 2x32 t][fn: 4x32 col]
    for (int ks = 0; ks < 8; ++ks) {
        int k0 = ks * 32;
        {
            f16x8 v = *(const f16x8*)(xa + (size_t)sa_t * D + k0 + sa_q * 8);
            int ba = sa_t * 64 + ((sa_q ^ ((sa_t >> 1) & 3)) << 4);
            *(f16x8*)(lds + ba) = v;
        }
        #pragma unroll
        for (int rr = 0; rr < 4; ++rr) {
            int r = rr * 128 + (tid >> 2);
            int c = tid & 3;
            f16x8 v = *(const f16x8*)(wb + (size_t)r * D + k0 + c * 8);
            int ba = 8192 + r * 64 + ((c ^ ((r >> 1) & 3)) << 4);
            *(f16x8*)(lds + ba) = v;
        }
        __syncthreads();
        // 32x32x16 operands: row/col = lane&31, k = (lane>>5)*8 + j
        f16x8 a[2][2], bfr[4][2];
        #pragma unroll
        for (int kk = 0; kk < 2; ++kk) {
            int cq = kk * 2 + hk;               // 8-f16 chunk index in [0,4)
            #pragma unroll
            for (int fm = 0; fm < 2; ++fm) {
                int t = wr * 64 + fm * 32 + l5;
                int ba = t * 64 + ((cq ^ ((t >> 1) & 3)) << 4);
                a[fm][kk] = *(const f16x8*)(lds + ba);
            }
            #pragma unroll
            for (int fn = 0; fn < 4; ++fn) {
                int c = wc * 128 + fn * 32 + l5;
                int ba = 8192 + c * 64 + ((cq ^ ((c >> 1) & 3)) << 4);
                bfr[fn][kk] = *(const f16x8*)(lds + ba);
            }
        }
        #pragma unroll
        for (int kk = 0; kk < 2; ++kk)
            #pragma unroll
            for (int fm = 0; fm < 2; ++fm)
                #pragma unroll
                for (int fn = 0; fn < 4; ++fn)
                    acc[fm][fn] = __builtin_amdgcn_mfma_f32_32x32x16_f16(
                        a[fm][kk], bfr[fn][kk], acc[fm][fn], 0, 0, 0);
        __syncthreads();
    }
    // epilogue: bias + f16, transpose via 32KB LDS window (128 cols x 128 t)
    // 32x32 C/D layout: col = lane&31, row = (reg&3) + 8*(reg>>2) + 4*(lane>>5)
    const float* bp = bml + (size_t)(8 + h * 8) * E;
    int b_g = t0 >> 11, tin = t0 & 2047;
    f16* obase = h ? Kt : Vt;
    for (int p = 0; p < 4; ++p) {
        if (wc == p) {
            #pragma unroll
            for (int fn = 0; fn < 4; ++fn) {
                int cc = fn * 32 + l5;         // 0..127 in window
                float bias = bp[p * 128 + cc];
                int swz = (cc & 7) << 4;
                #pragma unroll
                for (int fm = 0; fm < 2; ++fm) {
                    #pragma unroll
                    for (int reg = 0; reg < 16; reg += 2) {
                        int t = wr * 64 + fm * 32 + (reg & 3) + 8 * (reg >> 2) + 4 * hk;
                        union { f16 h2[2]; unsigned u; } pk;
                        pk.h2[0] = (f16)(acc[fm][fn][reg] + bias);
                        pk.h2[1] = (f16)(acc[fm][fn][reg + 1] + bias);
                        int ba = cc * 256 + ((t * 2) ^ swz);
                        *(unsigned*)(lds + ba) = pk.u;
                    }
                }
            }
        }
        __syncthreads();
        {
            int cc = tid >> 2, part = tid & 3;
            int cg = p * 128 + cc;
            int l = cg >> 6, e = cg & 63;
            f16* dst = obase + ((size_t)((b_g * L + l) * E + e)) * T + tin + part * 32;
            int swz = (cc & 7) << 4;
            #pragma unroll
            for (int jj = 0; jj < 4; ++jj) {
                int t = part * 32 + jj * 8;
                int ba = cc * 256 + ((t * 2) ^ swz);
                *(f16x8*)(dst + jj * 8) = *(const f16x8*)(lds + ba);
            }
        }
        __syncthreads();
    }
}

// ---------------------------------------------------------------------------
// K3: C = sum_t w_t v_t k_t^T via MFMA, with INLINE scan.  (R11, unchanged)
// ---------------------------------------------------------------------------
__global__ __launch_bounds__(256) void k_cgemm2s(const f16* __restrict__ Vt,
        const f16* __restrict__ Kt, const float* __restrict__ ibuf,
        const float* __restrict__ fbuf, float* __restrict__ Cpart) {
    __shared__ float red[64 * 64];
    __shared__ float redn[64];
    __shared__ float part[256];
    __shared__ float rmax[256];
    __shared__ __align__(16) f16 wlds[512];
    int tid = threadIdx.x;
    int bl = blockIdx.x, tc = blockIdx.y;
    int wv = tid >> 6, lane = tid & 63;
    {
        const float* fp = fbuf + bl * T + tid * 8;
        const float* ip = ibuf + bl * T + tid * 8;
        float4 fa = *(const float4*)fp;
        float4 fb = *(const float4*)(fp + 4);
        float4 ia = *(const float4*)ip;
        float4 ib = *(const float4*)(ip + 4);
        float f[8] = {fa.x, fa.y, fa.z, fa.w, fb.x, fb.y, fb.z, fb.w};
        float iv[8] = {ia.x, ia.y, ia.z, ia.w, ib.x, ib.y, ib.z, ib.w};
        float ls[8]; float run = 0.f;
        #pragma unroll
        for (int r = 0; r < 8; ++r) { run += f[r]; ls[r] = run; }
        part[tid] = run;
        __syncthreads();
        float inc = run;
        #pragma unroll
        for (int s = 1; s < 256; s <<= 1) {
            float u = (tid >= s) ? part[tid - s] : 0.f;
            __syncthreads();
            inc += u;
            part[tid] = inc;
            __syncthreads();
        }
        float off = inc - run;
        float e[8]; float lmax = -1e30f;
        #pragma unroll
        for (int r = 0; r < 8; ++r) { e[r] = iv[r] - (off + ls[r]); lmax = fmaxf(lmax, e[r]); }
        rmax[tid] = lmax;
        __syncthreads();
        for (int s = 128; s > 0; s >>= 1) {
            if (tid < s) rmax[tid] = fmaxf(rmax[tid], rmax[tid + s]);
            __syncthreads();
        }
        float M = fmaxf(rmax[0], 0.0f);
        int t = tid * 8;
        if ((t >> 9) == tc) {
            f16x8 w8;
            #pragma unroll
            for (int r = 0; r < 8; ++r) w8[r] = (f16)__expf(e[r] - M);
            *(f16x8*)&wlds[t & 511] = w8;
        }
        __syncthreads();
    }
    const f16* vp = Vt + (size_t)bl * E * T;
    const f16* kp = Kt + (size_t)bl * E * T;
    f32x4 acc[5][4] = {};
    int tbase = tc * 512 + wv * 128;
    for (int kc = 0; kc < 4; ++kc) {
        int tt = tbase + kc * 32 + (lane >> 4) * 8;
        f16x8 wfrag = *(const f16x8*)&wlds[tt & 511];
        f16x8 a[5], bf[4];
        #pragma unroll
        for (int m = 0; m < 4; ++m) {
            int i = m * 16 + (lane & 15);
            f16x8 v = *(const f16x8*)(vp + (size_t)i * T + tt);
            a[m] = v * wfrag;
        }
        a[4] = wfrag;
        #pragma unroll
        for (int nn = 0; nn < 4; ++nn) {
            int j = nn * 16 + (lane & 15);
            bf[nn] = *(const f16x8*)(kp + (size_t)j * T + tt);
        }
        #pragma unroll
        for (int m = 0; m < 5; ++m)
            #pragma unroll
            for (int nn = 0; nn < 4; ++nn)
                acc[m][nn] = __builtin_amdgcn_mfma_f32_16x16x32_f16(
                    a[m], bf[nn], acc[m][nn], 0, 0, 0);
    }
    for (int rr = 0; rr < 4; ++rr) {
        if (wv == rr) {
            #pragma unroll
            for (int m = 0; m < 4; ++m)
                #pragma unroll
                for (int nn = 0; nn < 4; ++nn)
                    #pragma unroll
                    for (int r = 0; r < 4; ++r) {
                        int row = m * 16 + (lane >> 4) * 4 + r;
                        int col = nn * 16 + (lane & 15);
                        if (rr == 0) red[row * 64 + col] = acc[m][nn][r];
                        else         red[row * 64 + col] += acc[m][nn][r];
                    }
            if ((lane >> 4) == 0) {
                #pragma unroll
                for (int nn = 0; nn < 4; ++nn) {
                    int col = nn * 16 + (lane & 15);
                    if (rr == 0) redn[col] = acc[4][nn][0];
                    else         redn[col] += acc[4][nn][0];
                }
            }
        }
        __syncthreads();
    }
    float* cp = Cpart + ((size_t)bl * 4 + tc) * 4160;
    #pragma unroll
    for (int j = 0; j < 4; ++j) {
        int idx = tid * 16 + j * 4;
        *(float4*)(cp + idx) = *(const float4*)(red + idx);
    }
    if (tid < 64) cp[4096 + tid] = redn[tid];
}

// ---------------------------------------------------------------------------
// K4: reduce 4 partials, o/q at t=T-1, final h, write h + C.  (R11, unchanged)
// ---------------------------------------------------------------------------
__global__ __launch_bounds__(256) void k_final(const float* __restrict__ x,
        const float* __restrict__ Wml, const float* __restrict__ bml,
        const float* __restrict__ Cpart, float* __restrict__ out) {
    __shared__ float Cs[E * E];
    __shared__ float xs[D];
    __shared__ float ns[E];
    __shared__ float os[E];
    __shared__ float qs[E];
    int tid = threadIdx.x;
    int bl = blockIdx.x; int b = bl >> 3, l = bl & 7;
    xs[tid] = x[((size_t)(b * T + (T - 1))) * D + tid];
    const float* cp = Cpart + (size_t)bl * 4 * 4160;
    #pragma unroll
    for (int j = 0; j < 4; ++j) {
        int idx = tid * 16 + j * 4;
        float4 s = {0, 0, 0, 0};
        #pragma unroll
        for (int p = 0; p < 4; ++p) {
            float4 v = *(const float4*)(cp + p * 4160 + idx);
            s.x += v.x; s.y += v.y; s.z += v.z; s.w += v.w;
        }
        *(float4*)&Cs[idx] = s;
        *(float4*)(out + 4096 + (size_t)bl * (E * E) + idx) = s;
    }
    if (tid < 64) {
        float s = 0.f;
        #pragma unroll
        for (int p = 0; p < 4; ++p) s += cp[p * 4160 + 4096 + tid];
        ns[tid] = s;
    }
    __syncthreads();
    if (tid < 128) {
        int gate = tid >> 6, e = tid & 63;
        int wrow = gate ? (3 * L + l) : l;
        const float* wpp = Wml + (size_t)wrow * D * E + e;
        float s = 0.f;
        for (int kk = 0; kk < D; ++kk) s += xs[kk] * wpp[kk * E];
        s += bml[wrow * E + e];
        if (gate) qs[e] = s; else os[e] = s;
    }
    __syncthreads();
    if (tid < 64) {
        int j = tid;
        float hc = 0.f;
        for (int i2 = 0; i2 < E; ++i2) hc += Cs[i2 * E + j] * qs[i2];
        float nq = 0.f;
        for (int i2 = 0; i2 < E; ++i2) nq += ns[i2] * qs[i2];
        float denom = fmaxf(nq, 1.0f);
        float sg = 1.0f / (1.0f + __expf(-os[j]));
        out[bl * E + j] = sg * hc / denom;
    }
}

extern "C" void kernel_launch(void* const* d_in, const int* in_sizes, int n_in,
                              void* d_out, int out_size, void* d_ws, size_t ws_size,
                              hipStream_t stream) {
    const float* x    = (const float*)d_in[0];
    const float* Wml  = (const float*)d_in[1];
    const float* bml  = (const float*)d_in[2];
    const float* Wlin = (const float*)d_in[3];
    const float* blin = (const float*)d_in[4];
    float* out = (float*)d_out;
    float* ws = (float*)d_ws;
    float* ibuf  = ws + OFF_I;
    float* fbuf  = ws + OFF_F;
    f16*   Wt16  = (f16*)(ws + OFF_WT);
    f16*   Vt    = (f16*)(ws + OFF_VT);
    f16*   Kt    = (f16*)(ws + OFF_KT);
    float* Cpart = ws + OFF_CP;
    f16*   x16   = (f16*)(ws + OFF_X16);

    k_prep_all<<<2576, 256, 0, stream>>>(x, Wlin, blin, Wml, ibuf, fbuf, Wt16, x16);
    k_vkproj4<<<dim3(BT / 128, 2), 512, 0, stream>>>(x16, Wt16, bml, Vt, Kt);
    k_cgemm2s<<<dim3(B * L, 4), 256, 0, stream>>>(Vt, Kt, ibuf, fbuf, Cpart);
    k_final<<<B * L, 256, 0, stream>>>(x, Wml, bml, Cpart, out);
}

// Round 13
// 65.321 us; speedup vs baseline: 1.0164x; 1.0164x over previous
//
#include <hip/hip_runtime.h>

#define B 8
#define T 2048
#define D 256
#define L 8
#define E 64
#define BT (B*T)

typedef _Float16 f16;
typedef f16 f16x8 __attribute__((ext_vector_type(8)));
typedef float f32x4 __attribute__((ext_vector_type(4)));

// workspace layout (float offsets)
#define OFF_I   0
#define OFF_F   (OFF_I  + B*L*T)            // fp32
#define OFF_WT  (OFF_F  + B*L*T)            // f16 16*E*D
#define OFF_VT  (OFF_WT + 16*E*D/2)         // f16 B*L*E*T
#define OFF_KT  (OFF_VT + B*L*E*T/2)
#define OFF_CP  (OFF_KT + B*L*E*T/2)        // fp32 64*4*4160
#define OFF_X16 (OFF_CP + 64*4*4160)        // f16 BT*D

// ---------------------------------------------------------------------------
// K1: fused prep.  bx<512: i/f projection; 512..527: v/k weight transpose;
//     528..2575: x fp32->f16 conversion.
// ---------------------------------------------------------------------------
__global__ __launch_bounds__(256) void k_prep_all(const float* __restrict__ x,
        const float* __restrict__ Wlin, const float* __restrict__ blin,
        const float* __restrict__ Wml,
        float* __restrict__ ibuf, float* __restrict__ fbuf,
        f16* __restrict__ Wt16, f16* __restrict__ x16) {
    __shared__ __align__(16) char smem[49920];
    int tid = threadIdx.x;
    int bx = blockIdx.x;
    if (bx < 512) {
        float (*xs)[260] = (float(*)[260])smem;            // 32 x 260
        float (*wsm)[260] = (float(*)[260])(smem + 33280); // 16 x 260
        int t0 = bx * 32;
        {
            int row = tid >> 3, q = tid & 7;
            const float* src = x + (size_t)(t0 + row) * D + q * 32;
            #pragma unroll
            for (int j = 0; j < 8; ++j) {
                float4 v = *(const float4*)(src + j * 4);
                *(float4*)&xs[row][q * 32 + j * 4] = v;
            }
        }
        {
            int row = tid >> 4, c0 = (tid & 15) * 16;
            const float* src = Wlin + row * D + c0;
            #pragma unroll
            for (int j = 0; j < 4; ++j) {
                float4 v = *(const float4*)(src + j * 4);
                *(float4*)&wsm[row][c0 + j * 4] = v;
            }
        }
        __syncthreads();
        int tl = tid >> 4, g = tid & 15;
        float acc0 = 0.f, acc1 = 0.f;
        for (int i = 0; i < D; ++i) {
            float wv = wsm[g][i];
            acc0 += xs[tl * 2 + 0][i] * wv;
            acc1 += xs[tl * 2 + 1][i] * wv;
        }
        float bias = blin[g];
        float acc[2] = {acc0 + bias, acc1 + bias};
        #pragma unroll
        for (int u = 0; u < 2; ++u) {
            int t = t0 + tl * 2 + u;
            int b = t >> 11, tt = t & 2047;
            if (g < 8) ibuf[(b * L + g) * T + tt] = acc[u];
            else       fbuf[(b * L + (g - 8)) * T + tt] = acc[u];
        }
    } else if (bx < 528) {
        float (*ts)[65] = (float(*)[65])smem;              // 64 x 65
        int vkrow = bx - 512;
        int wrow = 8 + vkrow;
        for (int dc = 0; dc < 4; ++dc) {
            int d0 = dc * 64;
            int r = tid >> 2, cq = (tid & 3) * 16;
            const float* src = Wml + ((size_t)wrow * D + d0 + r) * E + cq;
            #pragma unroll
            for (int j = 0; j < 16; j += 4) {
                float4 v = *(const float4*)(src + j);
                ts[r][cq + j] = v.x; ts[r][cq + j + 1] = v.y;
                ts[r][cq + j + 2] = v.z; ts[r][cq + j + 3] = v.w;
            }
            __syncthreads();
            int e = tid >> 2, dq = (tid & 3) * 16;
            f16* dst = Wt16 + ((size_t)vkrow * E + e) * D + d0 + dq;
            f16x8 o0, o1;
            #pragma unroll
            for (int j = 0; j < 8; ++j) {
                o0[j] = (f16)ts[dq + j][e];
                o1[j] = (f16)ts[dq + 8 + j][e];
            }
            *(f16x8*)dst = o0;
            *(f16x8*)(dst + 8) = o1;
            __syncthreads();
        }
    } else {
        int i = ((bx - 528) * 256 + tid) * 8;
        float4 v0 = *(const float4*)(x + i);
        float4 v1 = *(const float4*)(x + i + 4);
        f16x8 o;
        o[0] = (f16)v0.x; o[1] = (f16)v0.y; o[2] = (f16)v0.z; o[3] = (f16)v0.w;
        o[4] = (f16)v1.x; o[5] = (f16)v1.y; o[6] = (f16)v1.z; o[7] = (f16)v1.w;
        *(f16x8*)(x16 + i) = o;
    }
}

// ---------------------------------------------------------------------------
// K2: v,k projection via f16 MFMA.  Tile 128(M) x 512(N), BK=32, 512 thr.
// grid (BT/128, 2); by = h (0 -> v cols, 1 -> k cols).  Output (e,t).
// ---------------------------------------------------------------------------
__global__ __launch_bounds__(512) void k_vkproj3(const f16* __restrict__ x16,
        const f16* __restrict__ Wt16, const float* __restrict__ bml,
        f16* __restrict__ Vt, f16* __restrict__ Kt) {
    __shared__ __align__(16) char lds[40960];   // As 8KB | Bs 32KB
    int tid = threadIdx.x;
    int bx = blockIdx.x, h = blockIdx.y;
    int t0 = bx * 128;
    const f16* xa = x16 + (size_t)t0 * D;
    const f16* wb = Wt16 + (size_t)h * 8 * E * D;
    int wv = tid >> 6, lane = tid & 63;
    int wr = wv >> 2, wc = wv & 3;
    int q = lane >> 4, lr = lane & 15;
    int sa_t = tid >> 2, sa_q = tid & 3;
    f32x4 acc[4][8] = {};
    for (int ks = 0; ks < 8; ++ks) {
        int k0 = ks * 32;
        {
            f16x8 v = *(const f16x8*)(xa + (size_t)sa_t * D + k0 + sa_q * 8);
            int ba = sa_t * 64 + ((sa_q ^ ((sa_t >> 1) & 3)) << 4);
            *(f16x8*)(lds + ba) = v;
        }
        #pragma unroll
        for (int rr = 0; rr < 4; ++rr) {
            int r = rr * 128 + (tid >> 2);
            int c = tid & 3;
            f16x8 v = *(const f16x8*)(wb + (size_t)r * D + k0 + c * 8);
            int ba = 8192 + r * 64 + ((c ^ ((r >> 1) & 3)) << 4);
            *(f16x8*)(lds + ba) = v;
        }
        __syncthreads();
        f16x8 a[4], bf[8];
        #pragma unroll
        for (int m = 0; m < 4; ++m) {
            int t = wr * 64 + m * 16 + lr;
            int ba = t * 64 + ((q ^ ((t >> 1) & 3)) << 4);
            a[m] = *(const f16x8*)(lds + ba);
        }
        #pragma unroll
        for (int n = 0; n < 8; ++n) {
            int c = wc * 128 + n * 16 + lr;
            int ba = 8192 + c * 64 + ((q ^ ((c >> 1) & 3)) << 4);
            bf[n] = *(const f16x8*)(lds + ba);
        }
        #pragma unroll
        for (int m = 0; m < 4; ++m)
            #pragma unroll
            for (int n = 0; n < 8; ++n)
                acc[m][n] = __builtin_amdgcn_mfma_f32_16x16x32_f16(
                    a[m], bf[n], acc[m][n], 0, 0, 0);
        __syncthreads();
    }
    // epilogue: bias + f16, transpose via 32KB LDS window (128 cols x 128 t)
    const float* bp = bml + (size_t)(8 + h * 8) * E;
    int b_g = t0 >> 11, tin = t0 & 2047;
    f16* obase = h ? Kt : Vt;
    for (int p = 0; p < 4; ++p) {
        if (wc == p) {
            #pragma unroll
            for (int n = 0; n < 8; ++n) {
                int cc = n * 16 + lr;          // 0..127 in window
                float bias = bp[p * 128 + cc];
                int swz = (cc & 7) << 4;
                #pragma unroll
                for (int m = 0; m < 4; ++m) {
                    #pragma unroll
                    for (int r = 0; r < 4; r += 2) {
                        int t = wr * 64 + m * 16 + q * 4 + r;
                        union { f16 h2[2]; unsigned u; } pk;
                        pk.h2[0] = (f16)(acc[m][n][r] + bias);
                        pk.h2[1] = (f16)(acc[m][n][r + 1] + bias);
                        int ba = cc * 256 + ((t * 2) ^ swz);
                        *(unsigned*)(lds + ba) = pk.u;
                    }
                }
            }
        }
        __syncthreads();
        {
            int cc = tid >> 2, part = tid & 3;
            int cg = p * 128 + cc;
            int l = cg >> 6, e = cg & 63;
            f16* dst = obase + ((size_t)((b_g * L + l) * E + e)) * T + tin + part * 32;
            int swz = (cc & 7) << 4;
            #pragma unroll
            for (int jj = 0; jj < 4; ++jj) {
                int t = part * 32 + jj * 8;
                int ba = cc * 256 + ((t * 2) ^ swz);
                *(f16x8*)(dst + jj * 8) = *(const f16x8*)(lds + ba);
            }
        }
        __syncthreads();
    }
}

// ---------------------------------------------------------------------------
// K3: C = sum_t w_t v_t k_t^T via MFMA, with INLINE scan (recomputed per
// block; identical fp order in all tc-blocks -> deterministic).
// grid (64, 4).  Row-64 trick gives n_j.  4 partials per bl.
// ---------------------------------------------------------------------------
__global__ __launch_bounds__(256) void k_cgemm2s(const f16* __restrict__ Vt,
        const f16* __restrict__ Kt, const float* __restrict__ ibuf,
        const float* __restrict__ fbuf, float* __restrict__ Cpart) {
    __shared__ float red[64 * 64];
    __shared__ float redn[64];
    __shared__ float part[256];
    __shared__ float rmax[256];
    __shared__ __align__(16) f16 wlds[512];
    int tid = threadIdx.x;
    int bl = blockIdx.x, tc = blockIdx.y;
    int wv = tid >> 6, lane = tid & 63;
    // ---- inline scan over full T for this bl ----
    {
        const float* fp = fbuf + bl * T + tid * 8;
        const float* ip = ibuf + bl * T + tid * 8;
        float4 fa = *(const float4*)fp;
        float4 fb = *(const float4*)(fp + 4);
        float4 ia = *(const float4*)ip;
        float4 ib = *(const float4*)(ip + 4);
        float f[8] = {fa.x, fa.y, fa.z, fa.w, fb.x, fb.y, fb.z, fb.w};
        float iv[8] = {ia.x, ia.y, ia.z, ia.w, ib.x, ib.y, ib.z, ib.w};
        float ls[8]; float run = 0.f;
        #pragma unroll
        for (int r = 0; r < 8; ++r) { run += f[r]; ls[r] = run; }
        part[tid] = run;
        __syncthreads();
        float inc = run;
        #pragma unroll
        for (int s = 1; s < 256; s <<= 1) {
            float u = (tid >= s) ? part[tid - s] : 0.f;
            __syncthreads();
            inc += u;
            part[tid] = inc;
            __syncthreads();
        }
        float off = inc - run;
        float e[8]; float lmax = -1e30f;
        #pragma unroll
        for (int r = 0; r < 8; ++r) { e[r] = iv[r] - (off + ls[r]); lmax = fmaxf(lmax, e[r]); }
        rmax[tid] = lmax;
        __syncthreads();
        for (int s = 128; s > 0; s >>= 1) {
            if (tid < s) rmax[tid] = fmaxf(rmax[tid], rmax[tid + s]);
            __syncthreads();
        }
        float M = fmaxf(rmax[0], 0.0f);
        int t = tid * 8;
        if ((t >> 9) == tc) {
            f16x8 w8;
            #pragma unroll
            for (int r = 0; r < 8; ++r) w8[r] = (f16)__expf(e[r] - M);
            *(f16x8*)&wlds[t & 511] = w8;
        }
        __syncthreads();
    }
    // ---- weighted C-GEMM ----
    const f16* vp = Vt + (size_t)bl * E * T;
    const f16* kp = Kt + (size_t)bl * E * T;
    f32x4 acc[5][4] = {};
    int tbase = tc * 512 + wv * 128;
    for (int kc = 0; kc < 4; ++kc) {
        int tt = tbase + kc * 32 + (lane >> 4) * 8;
        f16x8 wfrag = *(const f16x8*)&wlds[tt & 511];
        f16x8 a[5], bf[4];
        #pragma unroll
        for (int m = 0; m < 4; ++m) {
            int i = m * 16 + (lane & 15);
            f16x8 v = *(const f16x8*)(vp + (size_t)i * T + tt);
            a[m] = v * wfrag;
        }
        a[4] = wfrag;
        #pragma unroll
        for (int nn = 0; nn < 4; ++nn) {
            int j = nn * 16 + (lane & 15);
            bf[nn] = *(const f16x8*)(kp + (size_t)j * T + tt);
        }
        #pragma unroll
        for (int m = 0; m < 5; ++m)
            #pragma unroll
            for (int nn = 0; nn < 4; ++nn)
                acc[m][nn] = __builtin_amdgcn_mfma_f32_16x16x32_f16(
                    a[m], bf[nn], acc[m][nn], 0, 0, 0);
    }
    for (int rr = 0; rr < 4; ++rr) {
        if (wv == rr) {
            #pragma unroll
            for (int m = 0; m < 4; ++m)
                #pragma unroll
                for (int nn = 0; nn < 4; ++nn)
                    #pragma unroll
                    for (int r = 0; r < 4; ++r) {
                        int row = m * 16 + (lane >> 4) * 4 + r;
                        int col = nn * 16 + (lane & 15);
                        if (rr == 0) red[row * 64 + col] = acc[m][nn][r];
                        else         red[row * 64 + col] += acc[m][nn][r];
                    }
            if ((lane >> 4) == 0) {
                #pragma unroll
                for (int nn = 0; nn < 4; ++nn) {
                    int col = nn * 16 + (lane & 15);
                    if (rr == 0) redn[col] = acc[4][nn][0];
                    else         redn[col] += acc[4][nn][0];
                }
            }
        }
        __syncthreads();
    }
    float* cp = Cpart + ((size_t)bl * 4 + tc) * 4160;
    #pragma unroll
    for (int j = 0; j < 4; ++j) {
        int idx = tid * 16 + j * 4;
        *(float4*)(cp + idx) = *(const float4*)(red + idx);
    }
    if (tid < 64) cp[4096 + tid] = redn[tid];
}

// ---------------------------------------------------------------------------
// K4: reduce 4 partials, o/q at t=T-1, final h, write h + C.
// ---------------------------------------------------------------------------
__global__ __launch_bounds__(256) void k_final(const float* __restrict__ x,
        const float* __restrict__ Wml, const float* __restrict__ bml,
        const float* __restrict__ Cpart, float* __restrict__ out) {
    __shared__ float Cs[E * E];
    __shared__ float xs[D];
    __shared__ float ns[E];
    __shared__ float os[E];
    __shared__ float qs[E];
    int tid = threadIdx.x;
    int bl = blockIdx.x; int b = bl >> 3, l = bl & 7;
    xs[tid] = x[((size_t)(b * T + (T - 1))) * D + tid];
    const float* cp = Cpart + (size_t)bl * 4 * 4160;
    #pragma unroll
    for (int j = 0; j < 4; ++j) {
        int idx = tid * 16 + j * 4;
        float4 s = {0, 0, 0, 0};
        #pragma unroll
        for (int p = 0; p < 4; ++p) {
            float4 v = *(const float4*)(cp + p * 4160 + idx);
            s.x += v.x; s.y += v.y; s.z += v.z; s.w += v.w;
        }
        *(float4*)&Cs[idx] = s;
        *(float4*)(out + 4096 + (size_t)bl * (E * E) + idx) = s;
    }
    if (tid < 64) {
        float s = 0.f;
        #pragma unroll
        for (int p = 0; p < 4; ++p) s += cp[p * 4160 + 4096 + tid];
        ns[tid] = s;
    }
    __syncthreads();
    if (tid < 128) {
        int gate = tid >> 6, e = tid & 63;
        int wrow = gate ? (3 * L + l) : l;
        const float* wpp = Wml + (size_t)wrow * D * E + e;
        float s = 0.f;
        for (int kk = 0; kk < D; ++kk) s += xs[kk] * wpp[kk * E];
        s += bml[wrow * E + e];
        if (gate) qs[e] = s; else os[e] = s;
    }
    __syncthreads();
    if (tid < 64) {
        int j = tid;
        float hc = 0.f;
        for (int i2 = 0; i2 < E; ++i2) hc += Cs[i2 * E + j] * qs[i2];
        float nq = 0.f;
        for (int i2 = 0; i2 < E; ++i2) nq += ns[i2] * qs[i2];
        float denom = fmaxf(nq, 1.0f);
        float sg = 1.0f / (1.0f + __expf(-os[j]));
        out[bl * E + j] = sg * hc / denom;
    }
}

extern "C" void kernel_launch(void* const* d_in, const int* in_sizes, int n_in,
                              void* d_out, int out_size, void* d_ws, size_t ws_size,
                              hipStream_t stream) {
    const float* x    = (const float*)d_in[0];
    const float* Wml  = (const float*)d_in[1];
    const float* bml  = (const float*)d_in[2];
    const float* Wlin = (const float*)d_in[3];
    const float* blin = (const float*)d_in[4];
    float* out = (float*)d_out;
    float* ws = (float*)d_ws;
    float* ibuf  = ws + OFF_I;
    float* fbuf  = ws + OFF_F;
    f16*   Wt16  = (f16*)(ws + OFF_WT);
    f16*   Vt    = (f16*)(ws + OFF_VT);
    f16*   Kt    = (f16*)(ws + OFF_KT);
    float* Cpart = ws + OFF_CP;
    f16*   x16   = (f16*)(ws + OFF_X16);

    k_prep_all<<<2576, 256, 0, stream>>>(x, Wlin, blin, Wml, ibuf, fbuf, Wt16, x16);
    k_vkproj3<<<dim3(BT / 128, 2), 512, 0, stream>>>(x16, Wt16, bml, Vt, Kt);
    k_cgemm2s<<<dim3(B * L, 4), 256, 0, stream>>>(Vt, Kt, ibuf, fbuf, Cpart);
    k_final<<<B * L, 256, 0, stream>>>(x, Wml, bml, Cpart, out);
}